// Round 14
// baseline (630.209 us; speedup 1.0000x reference)
//
#include <hip/hip_runtime.h>

#define BLOCK 256
#define NB 5      // objects per scene
#define DD 12     // per-object feature dim
#define EE 64     // goal embedding dim
#define HH 32     // F1 hidden dim
#define ROW 81    // D + E + N
#define OUTW 405  // N * ROW
#define TILE 64   // rows per block in assemble kernel
#define W1P 28    // padded W1^T row stride
#define SBS 164   // s_b scene stride (5*32 + 4: 16B-aligned, ~2-way banks)
#define SPB 48    // scenes per block in zhat kernel (4 waves x 12)

// ---------------- K1: g2[B,32] = W2 @ ghat, 4 threads/scene ----------------
__global__ __launch_bounds__(BLOCK) void g2_kernel(
    const float* __restrict__ ghat, const float* __restrict__ W2,
    float* __restrict__ g2buf, int g2stride, int g2off, int g2vec, int B)
{
    const int tid = threadIdx.x;
    const int q = tid & 3;                       // h-oct selector
    const int sc = blockIdx.x * 64 + (tid >> 2); // scene
    const bool act = (sc < B);
    const int ic = act ? sc : (B - 1);

    const float4* grow = reinterpret_cast<const float4*>(ghat + (size_t)ic * EE);
    float acc[8];
    #pragma unroll
    for (int r = 0; r < 8; ++r) acc[r] = 0.f;

    #pragma unroll
    for (int ec = 0; ec < EE / 4; ++ec) {
        const float4 gv = grow[ec];
        #pragma unroll
        for (int r = 0; r < 8; ++r) {
            const float4 wv = reinterpret_cast<const float4*>(W2 + (q * 8 + r) * EE)[ec]; // L1-hot
            acc[r] += (gv.x * wv.x + gv.y * wv.y) + (gv.z * wv.z + gv.w * wv.w);
        }
    }
    if (act) {
        float* dst = g2buf + (size_t)ic * g2stride + g2off + q * 8;
        if (g2vec) {
            reinterpret_cast<float4*>(dst)[0] = make_float4(acc[0], acc[1], acc[2], acc[3]);
            reinterpret_cast<float4*>(dst)[1] = make_float4(acc[4], acc[5], acc[6], acc[7]);
        } else {
            #pragma unroll
            for (int r = 0; r < 8; ++r) dst[r] = acc[r];
        }
    }
}

// ---------------- K2: zhat[B,5], 5 threads per scene ----------------
// lane = grp*5 + j (12 scenes/wave, lanes 60-63 idle). Thread computes
// a_j[32] (regs) + b_j[32] -> LDS; pair loop reads b_k/g2/w2s in b128 chunks;
// softmax via 5-lane group shfl reduce. State ~86 floats -> fits 128 cap.
__global__ __launch_bounds__(BLOCK, 2) void zhat_kernel(
    const float* __restrict__ obs, const float* __restrict__ W1,
    const float* __restrict__ b1, const float* __restrict__ W2,
    const float* __restrict__ b2,
    const float* __restrict__ g2buf, int g2stride, int g2off, int g2vec,
    float* __restrict__ zbuf, int zstride, int zoff, int B)
{
    __shared__ float s_W1t[HH * W1P];   // W1^T [h][d<24], uniform broadcast reads
    __shared__ float s_b1[HH];
    __shared__ float s_w2s[HH];         // rowsum(W2)
    __shared__ float s_sb2;             // sum(b2)
    __shared__ float s_b[SPB * SBS];    // b rows: [scene][j][32]

    const int tid = threadIdx.x;

    // ---- stage W1^T (coalesced read), b1, w2s, sb2 ----
    for (int idx = tid; idx < 2 * DD * HH; idx += BLOCK) {
        const int h = idx & (HH - 1);   // idx = d*32 + h
        const int d = idx >> 5;
        s_W1t[h * W1P + d] = W1[idx];
    }
    if (tid < HH) {
        s_b1[tid] = b1[tid];
        float s = 0.f;
        const float4* p = reinterpret_cast<const float4*>(W2 + tid * EE);
        #pragma unroll
        for (int qq = 0; qq < EE / 4; ++qq) { float4 v = p[qq]; s += (v.x + v.y) + (v.z + v.w); }
        s_w2s[tid] = s;
    } else if (tid == HH) {
        float s = 0.f;
        #pragma unroll
        for (int e = 0; e < EE; ++e) s += b2[e];
        s_sb2 = s;
    }

    const int lane = tid & 63;
    const int wv   = tid >> 6;
    const int grp  = lane / 5;                 // 12 => idle lane
    const int j    = lane - grp * 5;
    const bool on  = (grp < 12);
    const int sBlk = wv * 12 + (on ? grp : 0); // LDS scene slot (clamped)
    const int i    = blockIdx.x * SPB + wv * 12 + grp;
    const bool act = on && (i < B);
    const int ic   = act ? i : (B - 1);        // clamp loads; stores guarded

    // ---- my obs row (12 floats; 5-lane group covers 60 contiguous) ----
    float o[DD];
    {
        const float4* p = reinterpret_cast<const float4*>(obs + (size_t)ic * (NB * DD) + j * DD);
        #pragma unroll
        for (int qq = 0; qq < 3; ++qq) {
            float4 v = p[qq];
            o[4*qq+0] = v.x; o[4*qq+1] = v.y; o[4*qq+2] = v.z; o[4*qq+3] = v.w;
        }
    }
    __syncthreads();   // s_W1t / s_b1 / s_w2s / s_sb2 ready

    // ---- phase 1: a_j[32] (regs), b_j[32] -> LDS ----
    float a[HH], b[HH];
    #pragma unroll
    for (int h = 0; h < HH; ++h) {
        const float* w1r = &s_W1t[h * W1P];
        const float4 t0 = *reinterpret_cast<const float4*>(w1r + 0);
        const float4 t1 = *reinterpret_cast<const float4*>(w1r + 4);
        const float4 t2 = *reinterpret_cast<const float4*>(w1r + 8);
        const float4 u0 = *reinterpret_cast<const float4*>(w1r + 12);
        const float4 u1 = *reinterpret_cast<const float4*>(w1r + 16);
        const float4 u2 = *reinterpret_cast<const float4*>(w1r + 20);
        a[h] = s_b1[h]
             + ((o[0]*t0.x + o[1]*t0.y) + (o[2]*t0.z + o[3]*t0.w))
             + ((o[4]*t1.x + o[5]*t1.y) + (o[6]*t1.z + o[7]*t1.w))
             + ((o[8]*t2.x + o[9]*t2.y) + (o[10]*t2.z + o[11]*t2.w));
        b[h] = ((o[0]*u0.x + o[1]*u0.y) + (o[2]*u0.z + o[3]*u0.w))
             + ((o[4]*u1.x + o[5]*u1.y) + (o[6]*u1.z + o[7]*u1.w))
             + ((o[8]*u2.x + o[9]*u2.y) + (o[10]*u2.z + o[11]*u2.w));
    }
    if (on) {
        float4* dst = reinterpret_cast<float4*>(&s_b[sBlk * SBS + j * HH]);
        #pragma unroll
        for (int c = 0; c < 8; ++c)
            dst[c] = make_float4(b[4*c+0], b[4*c+1], b[4*c+2], b[4*c+3]);
    }
    __syncthreads();   // s_b ready

    // ---- pair loop: w[k], hp[k] over 32 h in 4 chunks of 8 ----
    float w[NB], hp[NB];
    #pragma unroll
    for (int k = 0; k < NB; ++k) { w[k] = 0.f; hp[k] = 0.f; }

    const float* gp = g2buf + (size_t)ic * g2stride + g2off;
    #pragma unroll
    for (int c = 0; c < 4; ++c) {
        float w2c[8], g2c[8];
        {
            const float4* up = reinterpret_cast<const float4*>(&s_w2s[c * 8]);
            const float4 u0 = up[0], u1 = up[1];
            w2c[0]=u0.x; w2c[1]=u0.y; w2c[2]=u0.z; w2c[3]=u0.w;
            w2c[4]=u1.x; w2c[5]=u1.y; w2c[6]=u1.z; w2c[7]=u1.w;
        }
        if (g2vec) {
            const float4* gv = reinterpret_cast<const float4*>(gp + c * 8);
            const float4 v0 = gv[0], v1 = gv[1];
            g2c[0]=v0.x; g2c[1]=v0.y; g2c[2]=v0.z; g2c[3]=v0.w;
            g2c[4]=v1.x; g2c[5]=v1.y; g2c[6]=v1.z; g2c[7]=v1.w;
        } else {
            #pragma unroll
            for (int e = 0; e < 8; ++e) g2c[e] = gp[c * 8 + e];
        }
        #pragma unroll
        for (int k = 0; k < NB; ++k) {
            const float4* bp = reinterpret_cast<const float4*>(&s_b[sBlk * SBS + k * HH + c * 8]);
            const float4 b0 = bp[0], b1v = bp[1];
            const float bl[8] = {b0.x, b0.y, b0.z, b0.w, b1v.x, b1v.y, b1v.z, b1v.w};
            #pragma unroll
            for (int e = 0; e < 8; ++e) {
                const float hv = fmaxf(a[c*8 + e] + bl[e], 0.f);
                w[k]  += hv * g2c[e];
                hp[k] += hv * w2c[e];
            }
        }
    }

    // ---- softmax across 5-lane group; thread owns row j ----
    const int base5 = grp * 5;
    float mm = w[0];
    #pragma unroll
    for (int k = 1; k < NB; ++k) mm = fmaxf(mm, w[k]);
    float m = mm;
    #pragma unroll
    for (int k = 0; k < NB; ++k) m = fmaxf(m, __shfl(mm, base5 + k));

    float r = 0.f, z = 0.f;
    #pragma unroll
    for (int k = 0; k < NB; ++k) {
        const float e = __expf(w[k] - m);
        r += e;
        z += e * hp[k];
    }
    float l = 0.f;
    #pragma unroll
    for (int k = 0; k < NB; ++k) l += __shfl(r, base5 + k);

    if (act)
        zbuf[(size_t)i * zstride + zoff + j] = (z + s_sb2 * r) / l;
}

// ---------------- K3: assemble output (proven R3 path) ----------------
__global__ __launch_bounds__(BLOCK) void assemble_kernel(
    const float* __restrict__ obs, const float* __restrict__ ghat,
    const float* __restrict__ zbuf, int zstride, int zoff,
    float* __restrict__ out, int B)
{
    __shared__ float s_obs[TILE * NB * DD];
    __shared__ float s_gh[TILE * EE];
    __shared__ float s_zh[TILE * NB];

    const int tid = threadIdx.x;
    const int r0 = blockIdx.x * TILE;
    const int rows = (B - r0 < TILE) ? (B - r0) : TILE;

    for (int t = tid; t < rows * NB * DD; t += BLOCK)
        s_obs[t] = obs[(size_t)r0 * NB * DD + t];
    for (int t = tid; t < rows * EE; t += BLOCK)
        s_gh[t] = ghat[(size_t)r0 * EE + t];
    for (int t = tid; t < rows * NB; t += BLOCK) {
        const int row = t / NB, k = t - row * NB;
        s_zh[t] = zbuf[(size_t)(r0 + row) * zstride + zoff + k];
    }
    __syncthreads();

    const size_t base = (size_t)r0 * OUTW;
    for (int t = tid; t < rows * OUTW; t += BLOCK) {
        const int il = t / OUTW;
        const int r  = t - il * OUTW;
        const int j  = r / ROW;
        const int rr = r - j * ROW;
        float v;
        if (rr < DD)           v = s_obs[il * NB * DD + j * DD + rr];
        else if (rr < DD + EE) v = s_gh[il * EE + (rr - DD)];
        else                   v = s_zh[il * NB + (rr - (DD + EE))];
        out[base + t] = v;
    }
}

extern "C" void kernel_launch(void* const* d_in, const int* in_sizes, int n_in,
                              void* d_out, int out_size, void* d_ws, size_t ws_size,
                              hipStream_t stream) {
    const float* obs  = (const float*)d_in[0];
    const float* ghat = (const float*)d_in[1];
    const float* W1   = (const float*)d_in[2];
    const float* b1   = (const float*)d_in[3];
    const float* W2   = (const float*)d_in[4];
    const float* b2   = (const float*)d_in[5];
    float* out = (float*)d_out;

    const int B = in_sizes[0] / (NB * DD);

    // scratch layout: g2 (B*32) + zhat (B*5) in d_ws when it fits;
    // otherwise stash inside out rows (g2 @ cols 360..391, zhat @ 400..404 --
    // disjoint; assemble reads stashes before overwriting, stream-ordered).
    const size_t needG2 = (size_t)B * HH * sizeof(float);
    const size_t needZ  = (size_t)B * NB * sizeof(float);
    float *g2buf, *zbuf;
    int g2stride, g2off, g2vec, zstride, zoff;
    if (ws_size >= needG2 + needZ) {
        g2buf = (float*)d_ws;            g2stride = HH;   g2off = 0;   g2vec = 1;
        zbuf  = (float*)d_ws + (size_t)B * HH; zstride = NB; zoff = 0;
    } else if (ws_size >= needZ) {
        g2buf = out;  g2stride = OUTW;  g2off = 360;  g2vec = 0;
        zbuf  = (float*)d_ws;  zstride = NB;  zoff = 0;
    } else {
        g2buf = out;  g2stride = OUTW;  g2off = 360;  g2vec = 0;
        zbuf  = out;  zstride = OUTW;   zoff = OUTW - NB;
    }

    const int grid1 = (B + 63) / 64;
    hipLaunchKernelGGL(g2_kernel, dim3(grid1), dim3(BLOCK), 0, stream,
                       ghat, W2, g2buf, g2stride, g2off, g2vec, B);

    const int grid2 = (B + SPB - 1) / SPB;
    hipLaunchKernelGGL(zhat_kernel, dim3(grid2), dim3(BLOCK), 0, stream,
                       obs, W1, b1, W2, b2, g2buf, g2stride, g2off, g2vec,
                       zbuf, zstride, zoff, B);

    const int grid3 = (B + TILE - 1) / TILE;
    hipLaunchKernelGGL(assemble_kernel, dim3(grid3), dim3(BLOCK), 0, stream,
                       obs, ghat, zbuf, zstride, zoff, out, B);
}

// Round 15
// 326.941 us; speedup vs baseline: 1.9276x; 1.9276x over previous
//
#include <hip/hip_runtime.h>

#define BLOCK 256
#define NB 5      // objects per scene
#define DD 12     // per-object feature dim
#define EE 64     // goal embedding dim
#define HH 32     // F1 hidden dim
#define ROW 81    // D + E + N
#define OUTW 405  // N * ROW
#define TILE 64   // rows per block in assemble kernel
#define W1P 28    // padded W1^T row stride (112B, 16B-aligned)
#define SBS 164   // s_b scene stride floats (5*32+4: b128-aligned, 2-way banks)
#define SPB 48    // scenes per block in zhat kernel (4 waves x 12)

// ---------------- K1: g2[B,32] = W2 @ ghat, 4 threads/scene ----------------
__global__ __launch_bounds__(BLOCK) void g2_kernel(
    const float* __restrict__ ghat, const float* __restrict__ W2,
    float* __restrict__ g2buf, int g2stride, int g2off, int g2vec, int B)
{
    const int tid = threadIdx.x;
    const int q = tid & 3;                       // h-oct selector
    const int sc = blockIdx.x * 64 + (tid >> 2); // scene
    const bool act = (sc < B);
    const int ic = act ? sc : (B - 1);

    const float4* grow = reinterpret_cast<const float4*>(ghat + (size_t)ic * EE);
    float acc[8];
    #pragma unroll
    for (int r = 0; r < 8; ++r) acc[r] = 0.f;

    #pragma unroll
    for (int ec = 0; ec < EE / 4; ++ec) {
        const float4 gv = grow[ec];
        #pragma unroll
        for (int r = 0; r < 8; ++r) {
            const float4 wv = reinterpret_cast<const float4*>(W2 + (q * 8 + r) * EE)[ec]; // L1-hot
            acc[r] += (gv.x * wv.x + gv.y * wv.y) + (gv.z * wv.z + gv.w * wv.w);
        }
    }
    if (act) {
        float* dst = g2buf + (size_t)ic * g2stride + g2off + q * 8;
        if (g2vec) {
            reinterpret_cast<float4*>(dst)[0] = make_float4(acc[0], acc[1], acc[2], acc[3]);
            reinterpret_cast<float4*>(dst)[1] = make_float4(acc[4], acc[5], acc[6], acc[7]);
        } else {
            #pragma unroll
            for (int r = 0; r < 8; ++r) dst[r] = acc[r];
        }
    }
}

// ---------------- K2: zhat[B,5], 5 threads/scene, h in 4 chunks of 8 ----------------
// lane = grp*5 + j (12 scenes/wave, lanes 60-63 idle). Per chunk: thread
// computes a8/b8 for its row (W1^T via uniform LDS broadcast), parks b8 in
// LDS, barrier, accumulates w[5]/hp[5] from partner rows (broadcast b128
// reads). Max live state ~40 floats -> no spill possible, 4 waves/SIMD.
__global__ void zhat_kernel(
    const float* __restrict__ obs, const float* __restrict__ W1,
    const float* __restrict__ b1, const float* __restrict__ W2,
    const float* __restrict__ b2,
    const float* __restrict__ g2buf, int g2stride, int g2off, int g2vec,
    float* __restrict__ zbuf, int zstride, int zoff, int B)
{
    __shared__ float s_W1t[HH * W1P];   // W1^T [h][d<24]
    __shared__ float s_b1[HH];
    __shared__ float s_w2s[HH];         // rowsum(W2)
    __shared__ float s_sb2;             // sum(b2)
    __shared__ float s_b[SPB * SBS];    // b rows: [scene][j][32]

    const int tid = threadIdx.x;

    // ---- stage W1^T (coalesced read), b1, w2s, sb2 ----
    for (int idx = tid; idx < 2 * DD * HH; idx += BLOCK) {
        const int h = idx & (HH - 1);   // idx = d*32 + h
        const int d = idx >> 5;
        s_W1t[h * W1P + d] = W1[idx];
    }
    if (tid < HH) {
        s_b1[tid] = b1[tid];
        float s = 0.f;
        const float4* p = reinterpret_cast<const float4*>(W2 + tid * EE);
        #pragma unroll
        for (int qq = 0; qq < EE / 4; ++qq) { float4 v = p[qq]; s += (v.x + v.y) + (v.z + v.w); }
        s_w2s[tid] = s;
    } else if (tid == HH) {
        float s = 0.f;
        #pragma unroll
        for (int e = 0; e < EE; ++e) s += b2[e];
        s_sb2 = s;
    }

    const int lane = tid & 63;
    const int wv   = tid >> 6;
    const int grp  = lane / 5;                 // 12 => idle lane
    const int j    = lane - grp * 5;
    const bool on  = (grp < 12);
    const int sBlk = wv * 12 + (on ? grp : 0); // LDS scene slot (clamped)
    const int i    = blockIdx.x * SPB + wv * 12 + grp;
    const bool act = on && (i < B);
    const int ic   = act ? i : (B - 1);        // clamp loads; stores guarded

    // ---- my obs row (12 floats; 5-lane group covers 60 contiguous) ----
    float o[DD];
    {
        const float4* p = reinterpret_cast<const float4*>(obs + (size_t)ic * (NB * DD) + j * DD);
        #pragma unroll
        for (int qq = 0; qq < 3; ++qq) {
            float4 v = p[qq];
            o[4*qq+0] = v.x; o[4*qq+1] = v.y; o[4*qq+2] = v.z; o[4*qq+3] = v.w;
        }
    }
    __syncthreads();   // weights staged

    float w[NB], hp[NB];
    #pragma unroll
    for (int k = 0; k < NB; ++k) { w[k] = 0.f; hp[k] = 0.f; }
    const float* gp = g2buf + (size_t)ic * g2stride + g2off;

    #pragma unroll 1
    for (int c = 0; c < 4; ++c) {
        // ---- a8/b8 for h = c*8..c*8+7 (uniform h -> broadcast LDS reads) ----
        float a8[8], b8[8];
        #pragma unroll
        for (int hq = 0; hq < 8; ++hq) {
            const int h = c * 8 + hq;
            const float* w1r = &s_W1t[h * W1P];
            const float4 t0 = *reinterpret_cast<const float4*>(w1r + 0);
            const float4 t1 = *reinterpret_cast<const float4*>(w1r + 4);
            const float4 t2 = *reinterpret_cast<const float4*>(w1r + 8);
            a8[hq] = s_b1[h]
                 + ((o[0]*t0.x + o[1]*t0.y) + (o[2]*t0.z + o[3]*t0.w))
                 + ((o[4]*t1.x + o[5]*t1.y) + (o[6]*t1.z + o[7]*t1.w))
                 + ((o[8]*t2.x + o[9]*t2.y) + (o[10]*t2.z + o[11]*t2.w));
            const float4 u0 = *reinterpret_cast<const float4*>(w1r + 12);
            const float4 u1 = *reinterpret_cast<const float4*>(w1r + 16);
            const float4 u2 = *reinterpret_cast<const float4*>(w1r + 20);
            b8[hq] = ((o[0]*u0.x + o[1]*u0.y) + (o[2]*u0.z + o[3]*u0.w))
                 + ((o[4]*u1.x + o[5]*u1.y) + (o[6]*u1.z + o[7]*u1.w))
                 + ((o[8]*u2.x + o[9]*u2.y) + (o[10]*u2.z + o[11]*u2.w));
        }
        if (on) {
            float4* dst = reinterpret_cast<float4*>(&s_b[sBlk * SBS + j * HH + c * 8]);
            dst[0] = make_float4(b8[0], b8[1], b8[2], b8[3]);
            dst[1] = make_float4(b8[4], b8[5], b8[6], b8[7]);
        }
        __syncthreads();   // chunk's b rows visible (disjoint slices across chunks)

        // ---- pair accumulation for my row j against all k ----
        float g2c[8];
        if (g2vec) {
            const float4* gv4 = reinterpret_cast<const float4*>(gp + c * 8);
            const float4 v0 = gv4[0], v1 = gv4[1];
            g2c[0]=v0.x; g2c[1]=v0.y; g2c[2]=v0.z; g2c[3]=v0.w;
            g2c[4]=v1.x; g2c[5]=v1.y; g2c[6]=v1.z; g2c[7]=v1.w;
        } else {
            #pragma unroll
            for (int e = 0; e < 8; ++e) g2c[e] = gp[c * 8 + e];
        }
        float w2c[8];
        {
            const float4* up = reinterpret_cast<const float4*>(&s_w2s[c * 8]);
            const float4 u0 = up[0], u1 = up[1];
            w2c[0]=u0.x; w2c[1]=u0.y; w2c[2]=u0.z; w2c[3]=u0.w;
            w2c[4]=u1.x; w2c[5]=u1.y; w2c[6]=u1.z; w2c[7]=u1.w;
        }
        #pragma unroll
        for (int k = 0; k < NB; ++k) {
            const float4* bp = reinterpret_cast<const float4*>(&s_b[sBlk * SBS + k * HH + c * 8]);
            const float4 b0 = bp[0], b1v = bp[1];   // 5-lane broadcast reads
            const float bl[8] = {b0.x, b0.y, b0.z, b0.w, b1v.x, b1v.y, b1v.z, b1v.w};
            #pragma unroll
            for (int e = 0; e < 8; ++e) {
                const float hv = fmaxf(a8[e] + bl[e], 0.f);
                w[k]  += hv * g2c[e];
                hp[k] += hv * w2c[e];
            }
        }
    }

    // ---- softmax across 5-lane group; thread owns row j (proven R13) ----
    const int base5 = (on ? grp : 0) * 5;
    float mm = w[0];
    #pragma unroll
    for (int k = 1; k < NB; ++k) mm = fmaxf(mm, w[k]);
    float m = mm;
    #pragma unroll
    for (int k = 0; k < NB; ++k) m = fmaxf(m, __shfl(mm, base5 + k));

    float r = 0.f, z = 0.f;
    #pragma unroll
    for (int k = 0; k < NB; ++k) {
        const float e = __expf(w[k] - m);
        r += e;
        z += e * hp[k];
    }
    float l = 0.f;
    #pragma unroll
    for (int k = 0; k < NB; ++k) l += __shfl(r, base5 + k);

    if (act)
        zbuf[(size_t)i * zstride + zoff + j] = (z + s_sb2 * r) / l;
}

// ---------------- K3: assemble output (proven R3 path) ----------------
__global__ __launch_bounds__(BLOCK) void assemble_kernel(
    const float* __restrict__ obs, const float* __restrict__ ghat,
    const float* __restrict__ zbuf, int zstride, int zoff,
    float* __restrict__ out, int B)
{
    __shared__ float s_obs[TILE * NB * DD];
    __shared__ float s_gh[TILE * EE];
    __shared__ float s_zh[TILE * NB];

    const int tid = threadIdx.x;
    const int r0 = blockIdx.x * TILE;
    const int rows = (B - r0 < TILE) ? (B - r0) : TILE;

    for (int t = tid; t < rows * NB * DD; t += BLOCK)
        s_obs[t] = obs[(size_t)r0 * NB * DD + t];
    for (int t = tid; t < rows * EE; t += BLOCK)
        s_gh[t] = ghat[(size_t)r0 * EE + t];
    for (int t = tid; t < rows * NB; t += BLOCK) {
        const int row = t / NB, k = t - row * NB;
        s_zh[t] = zbuf[(size_t)(r0 + row) * zstride + zoff + k];
    }
    __syncthreads();

    const size_t base = (size_t)r0 * OUTW;
    for (int t = tid; t < rows * OUTW; t += BLOCK) {
        const int il = t / OUTW;
        const int r  = t - il * OUTW;
        const int j  = r / ROW;
        const int rr = r - j * ROW;
        float v;
        if (rr < DD)           v = s_obs[il * NB * DD + j * DD + rr];
        else if (rr < DD + EE) v = s_gh[il * EE + (rr - DD)];
        else                   v = s_zh[il * NB + (rr - (DD + EE))];
        out[base + t] = v;
    }
}

extern "C" void kernel_launch(void* const* d_in, const int* in_sizes, int n_in,
                              void* d_out, int out_size, void* d_ws, size_t ws_size,
                              hipStream_t stream) {
    const float* obs  = (const float*)d_in[0];
    const float* ghat = (const float*)d_in[1];
    const float* W1   = (const float*)d_in[2];
    const float* b1   = (const float*)d_in[3];
    const float* W2   = (const float*)d_in[4];
    const float* b2   = (const float*)d_in[5];
    float* out = (float*)d_out;

    const int B = in_sizes[0] / (NB * DD);

    // scratch: g2 (B*32) + zhat (B*5) in d_ws when it fits; else stash in out
    // rows (g2 @ cols 360..391, zhat @ 400..404; assemble reads before write).
    const size_t needG2 = (size_t)B * HH * sizeof(float);
    const size_t needZ  = (size_t)B * NB * sizeof(float);
    float *g2buf, *zbuf;
    int g2stride, g2off, g2vec, zstride, zoff;
    if (ws_size >= needG2 + needZ) {
        g2buf = (float*)d_ws;            g2stride = HH;   g2off = 0;   g2vec = 1;
        zbuf  = (float*)d_ws + (size_t)B * HH; zstride = NB; zoff = 0;
    } else if (ws_size >= needZ) {
        g2buf = out;  g2stride = OUTW;  g2off = 360;  g2vec = 0;
        zbuf  = (float*)d_ws;  zstride = NB;  zoff = 0;
    } else {
        g2buf = out;  g2stride = OUTW;  g2off = 360;  g2vec = 0;
        zbuf  = out;  zstride = OUTW;   zoff = OUTW - NB;
    }

    const int grid1 = (B + 63) / 64;
    hipLaunchKernelGGL(g2_kernel, dim3(grid1), dim3(BLOCK), 0, stream,
                       ghat, W2, g2buf, g2stride, g2off, g2vec, B);

    const int grid2 = (B + SPB - 1) / SPB;
    hipLaunchKernelGGL(zhat_kernel, dim3(grid2), dim3(BLOCK), 0, stream,
                       obs, W1, b1, W2, b2, g2buf, g2stride, g2off, g2vec,
                       zbuf, zstride, zoff, B);

    const int grid3 = (B + TILE - 1) / TILE;
    hipLaunchKernelGGL(assemble_kernel, dim3(grid3), dim3(BLOCK), 0, stream,
                       obs, ghat, zbuf, zstride, zoff, out, B);
}

// Round 16
// 320.991 us; speedup vs baseline: 1.9633x; 1.0185x over previous
//
#include <hip/hip_runtime.h>

#define BLOCK 256
#define NB 5      // objects per scene
#define DD 12     // per-object feature dim
#define EE 64     // goal embedding dim
#define HH 32     // F1 hidden dim
#define ROW 81    // D + E + N
#define OUTW 405  // N * ROW
#define TILE 64   // rows per block in assemble kernel
#define W1P 28    // padded W1^T row stride (112B, 16B-aligned)
#define SBS 164   // s_b scene stride floats (5*32+4: b128-aligned)
#define G2S 36    // s_g2 scene stride floats (32+4: bank-spread, 144B 16B-aligned)
#define SPB 48    // scenes per block in zhat kernel (4 waves x 12)

// ---------------- K2: zhat[B,5], 5 threads/scene, fused GEMV ----------------
// lane = grp*5 + j (12 scenes/wave, lanes 60-63 idle).
// GEMV fused: thread owns h = j+5*hp (<=7 rows), W2 from L1; parks in s_g2.
// Then h in 4 chunks of 8: a8/b8 from W1^T (uniform LDS broadcast), b8 ->
// s_b, barrier, accumulate w[5]/hp[5] with broadcast b128 reads of partner
// rows + g2 chunk. Max live state ~56 floats -> no spill, high occupancy.
__global__ void zhat_kernel(
    const float* __restrict__ obs, const float* __restrict__ ghat,
    const float* __restrict__ W1, const float* __restrict__ b1,
    const float* __restrict__ W2, const float* __restrict__ b2,
    float* __restrict__ zbuf, int zstride, int zoff, int B)
{
    __shared__ float s_W1t[HH * W1P];   // W1^T [h][d<24]
    __shared__ float s_b1[HH];
    __shared__ float s_w2s[HH];         // rowsum(W2)
    __shared__ float s_sb2;             // sum(b2)
    __shared__ float s_g2[SPB * G2S];   // W2@ghat per scene
    __shared__ float s_b[SPB * SBS];    // b rows: [scene][j][32]

    const int tid = threadIdx.x;

    // ---- stage W1^T (coalesced read), b1, w2s, sb2 ----
    for (int idx = tid; idx < 2 * DD * HH; idx += BLOCK) {
        const int h = idx & (HH - 1);   // idx = d*32 + h
        const int d = idx >> 5;
        s_W1t[h * W1P + d] = W1[idx];
    }
    if (tid < HH) {
        s_b1[tid] = b1[tid];
        float s = 0.f;
        const float4* p = reinterpret_cast<const float4*>(W2 + tid * EE);
        #pragma unroll
        for (int qq = 0; qq < EE / 4; ++qq) { float4 v = p[qq]; s += (v.x + v.y) + (v.z + v.w); }
        s_w2s[tid] = s;
    } else if (tid == HH) {
        float s = 0.f;
        #pragma unroll
        for (int e = 0; e < EE; ++e) s += b2[e];
        s_sb2 = s;
    }

    const int lane = tid & 63;
    const int wv   = tid >> 6;
    const int grp  = lane / 5;                 // 12 => idle lane
    const int j    = lane - grp * 5;
    const bool on  = (grp < 12);
    const int sBlk = wv * 12 + (on ? grp : 0); // LDS scene slot (clamped)
    const int i    = blockIdx.x * SPB + wv * 12 + grp;
    const bool act = on && (i < B);
    const int ic   = act ? i : (B - 1);        // clamp loads; stores guarded

    // ---- my obs row (12 floats; 5-lane group covers 60 contiguous) ----
    float o[DD];
    {
        const float4* p = reinterpret_cast<const float4*>(obs + (size_t)ic * (NB * DD) + j * DD);
        #pragma unroll
        for (int qq = 0; qq < 3; ++qq) {
            float4 v = p[qq];
            o[4*qq+0] = v.x; o[4*qq+1] = v.y; o[4*qq+2] = v.z; o[4*qq+3] = v.w;
        }
    }

    // ---- fused GEMV: g2[h] = W2[h,:].ghat_i for owned h = j+5*hp ----
    {
        float g2own[7];
        #pragma unroll
        for (int hp = 0; hp < 7; ++hp) g2own[hp] = 0.f;
        const float* grow = ghat + (size_t)ic * EE;
        #pragma unroll 1
        for (int ec = 0; ec < 4; ++ec) {          // 16 e per chunk
            float gc[16];
            const float4* gp = reinterpret_cast<const float4*>(grow + ec * 16);
            #pragma unroll
            for (int qq = 0; qq < 4; ++qq) {
                float4 v = gp[qq];
                gc[4*qq+0] = v.x; gc[4*qq+1] = v.y; gc[4*qq+2] = v.z; gc[4*qq+3] = v.w;
            }
            #pragma unroll
            for (int hp = 0; hp < 7; ++hp) {
                const int h = j + 5 * hp;
                if (h < HH) {                      // exec-masked tail
                    const float4* wp = reinterpret_cast<const float4*>(W2 + h * EE + ec * 16);
                    #pragma unroll
                    for (int qv = 0; qv < 4; ++qv) {
                        const float4 wvv = wp[qv];         // L1-hot (8 KB)
                        g2own[hp] += (gc[4*qv+0] * wvv.x + gc[4*qv+1] * wvv.y)
                                   + (gc[4*qv+2] * wvv.z + gc[4*qv+3] * wvv.w);
                    }
                }
            }
        }
        if (on) {
            #pragma unroll
            for (int hp = 0; hp < 7; ++hp) {
                const int h = j + 5 * hp;
                if (h < HH) s_g2[sBlk * G2S + h] = g2own[hp];
            }
        }
    }
    __syncthreads();   // weights + s_g2 ready

    float w[NB], hp5[NB];
    #pragma unroll
    for (int k = 0; k < NB; ++k) { w[k] = 0.f; hp5[k] = 0.f; }

    #pragma unroll 1
    for (int c = 0; c < 4; ++c) {
        // ---- a8/b8 for h = c*8..c*8+7 (uniform h -> broadcast LDS reads) ----
        float a8[8], b8[8];
        #pragma unroll
        for (int hq = 0; hq < 8; ++hq) {
            const int h = c * 8 + hq;
            const float* w1r = &s_W1t[h * W1P];
            const float4 t0 = *reinterpret_cast<const float4*>(w1r + 0);
            const float4 t1 = *reinterpret_cast<const float4*>(w1r + 4);
            const float4 t2 = *reinterpret_cast<const float4*>(w1r + 8);
            a8[hq] = s_b1[h]
                 + ((o[0]*t0.x + o[1]*t0.y) + (o[2]*t0.z + o[3]*t0.w))
                 + ((o[4]*t1.x + o[5]*t1.y) + (o[6]*t1.z + o[7]*t1.w))
                 + ((o[8]*t2.x + o[9]*t2.y) + (o[10]*t2.z + o[11]*t2.w));
            const float4 u0 = *reinterpret_cast<const float4*>(w1r + 12);
            const float4 u1 = *reinterpret_cast<const float4*>(w1r + 16);
            const float4 u2 = *reinterpret_cast<const float4*>(w1r + 20);
            b8[hq] = ((o[0]*u0.x + o[1]*u0.y) + (o[2]*u0.z + o[3]*u0.w))
                 + ((o[4]*u1.x + o[5]*u1.y) + (o[6]*u1.z + o[7]*u1.w))
                 + ((o[8]*u2.x + o[9]*u2.y) + (o[10]*u2.z + o[11]*u2.w));
        }
        if (on) {
            float4* dst = reinterpret_cast<float4*>(&s_b[sBlk * SBS + j * HH + c * 8]);
            dst[0] = make_float4(b8[0], b8[1], b8[2], b8[3]);
            dst[1] = make_float4(b8[4], b8[5], b8[6], b8[7]);
        }
        __syncthreads();   // chunk's b rows visible (disjoint slices per chunk)

        // ---- pair accumulation for my row j against all k ----
        float g2c[8], w2c[8];
        {
            const float4* gv4 = reinterpret_cast<const float4*>(&s_g2[sBlk * G2S + c * 8]);
            const float4 v0 = gv4[0], v1 = gv4[1];   // 5-lane broadcast
            g2c[0]=v0.x; g2c[1]=v0.y; g2c[2]=v0.z; g2c[3]=v0.w;
            g2c[4]=v1.x; g2c[5]=v1.y; g2c[6]=v1.z; g2c[7]=v1.w;
            const float4* up = reinterpret_cast<const float4*>(&s_w2s[c * 8]);
            const float4 u0 = up[0], u1 = up[1];
            w2c[0]=u0.x; w2c[1]=u0.y; w2c[2]=u0.z; w2c[3]=u0.w;
            w2c[4]=u1.x; w2c[5]=u1.y; w2c[6]=u1.z; w2c[7]=u1.w;
        }
        #pragma unroll
        for (int k = 0; k < NB; ++k) {
            const float4* bp = reinterpret_cast<const float4*>(&s_b[sBlk * SBS + k * HH + c * 8]);
            const float4 b0 = bp[0], b1v = bp[1];   // 5-lane broadcast reads
            const float bl[8] = {b0.x, b0.y, b0.z, b0.w, b1v.x, b1v.y, b1v.z, b1v.w};
            #pragma unroll
            for (int e = 0; e < 8; ++e) {
                const float hv = fmaxf(a8[e] + bl[e], 0.f);
                w[k]   += hv * g2c[e];
                hp5[k] += hv * w2c[e];
            }
        }
    }

    // ---- softmax across 5-lane group; thread owns row j (proven R13/R15) ----
    const int base5 = (on ? grp : 0) * 5;
    float mm = w[0];
    #pragma unroll
    for (int k = 1; k < NB; ++k) mm = fmaxf(mm, w[k]);
    float m = mm;
    #pragma unroll
    for (int k = 0; k < NB; ++k) m = fmaxf(m, __shfl(mm, base5 + k));

    float r = 0.f, z = 0.f;
    #pragma unroll
    for (int k = 0; k < NB; ++k) {
        const float e = __expf(w[k] - m);
        r += e;
        z += e * hp5[k];
    }
    float l = 0.f;
    #pragma unroll
    for (int k = 0; k < NB; ++k) l += __shfl(r, base5 + k);

    if (act)
        zbuf[(size_t)i * zstride + zoff + j] = (z + s_sb2 * r) / l;
}

// ---------------- K3: assemble output (proven R3 path) ----------------
__global__ __launch_bounds__(BLOCK) void assemble_kernel(
    const float* __restrict__ obs, const float* __restrict__ ghat,
    const float* __restrict__ zbuf, int zstride, int zoff,
    float* __restrict__ out, int B)
{
    __shared__ float s_obs[TILE * NB * DD];
    __shared__ float s_gh[TILE * EE];
    __shared__ float s_zh[TILE * NB];

    const int tid = threadIdx.x;
    const int r0 = blockIdx.x * TILE;
    const int rows = (B - r0 < TILE) ? (B - r0) : TILE;

    for (int t = tid; t < rows * NB * DD; t += BLOCK)
        s_obs[t] = obs[(size_t)r0 * NB * DD + t];
    for (int t = tid; t < rows * EE; t += BLOCK)
        s_gh[t] = ghat[(size_t)r0 * EE + t];
    for (int t = tid; t < rows * NB; t += BLOCK) {
        const int row = t / NB, k = t - row * NB;
        s_zh[t] = zbuf[(size_t)(r0 + row) * zstride + zoff + k];
    }
    __syncthreads();

    const size_t base = (size_t)r0 * OUTW;
    for (int t = tid; t < rows * OUTW; t += BLOCK) {
        const int il = t / OUTW;
        const int r  = t - il * OUTW;
        const int j  = r / ROW;
        const int rr = r - j * ROW;
        float v;
        if (rr < DD)           v = s_obs[il * NB * DD + j * DD + rr];
        else if (rr < DD + EE) v = s_gh[il * EE + (rr - DD)];
        else                   v = s_zh[il * NB + (rr - (DD + EE))];
        out[base + t] = v;
    }
}

extern "C" void kernel_launch(void* const* d_in, const int* in_sizes, int n_in,
                              void* d_out, int out_size, void* d_ws, size_t ws_size,
                              hipStream_t stream) {
    const float* obs  = (const float*)d_in[0];
    const float* ghat = (const float*)d_in[1];
    const float* W1   = (const float*)d_in[2];
    const float* b1   = (const float*)d_in[3];
    const float* W2   = (const float*)d_in[4];
    const float* b2   = (const float*)d_in[5];
    float* out = (float*)d_out;

    const int B = in_sizes[0] / (NB * DD);

    // zhat scratch: d_ws (2.6 MB, proven to fit) else stash in out row tails.
    float* zbuf; int zstride, zoff;
    if (ws_size >= (size_t)B * NB * sizeof(float)) {
        zbuf = (float*)d_ws; zstride = NB;   zoff = 0;
    } else {
        zbuf = out;          zstride = OUTW; zoff = OUTW - NB;
    }

    const int grid2 = (B + SPB - 1) / SPB;
    hipLaunchKernelGGL(zhat_kernel, dim3(grid2), dim3(BLOCK), 0, stream,
                       obs, ghat, W1, b1, W2, b2, zbuf, zstride, zoff, B);

    const int grid3 = (B + TILE - 1) / TILE;
    hipLaunchKernelGGL(assemble_kernel, dim3(grid3), dim3(BLOCK), 0, stream,
                       obs, ghat, zbuf, zstride, zoff, out, B);
}

// Round 17
// 215.922 us; speedup vs baseline: 2.9187x; 1.4866x over previous
//
#include <hip/hip_runtime.h>

#define BLOCK 256
#define NB 5      // objects per scene
#define DD 12     // per-object feature dim
#define EE 64     // goal embedding dim
#define HH 32     // F1 hidden dim
#define ROW 81    // D + E + N
#define OUTW 405  // N * ROW
#define TILE 64   // rows per block in assemble kernel
#define W1P 28    // padded W1^T row stride (112B, 16B-aligned)
#define SBJ 36    // s_b j-stride (36 floats: bank-offset 4 per j, 16B-aligned)
#define SBS 184   // s_b scene stride (5*36+4: 736B, 16B-aligned)
#define G2S 36    // s_g2 scene stride floats
#define SPB 48    // scenes per block in zhat kernel (4 waves x 12)

// ---------------- K2: zhat[B,5], 5 threads/scene, fused GEMV ----------------
// lane = grp*5 + j (12 scenes/wave, lanes 60-63 idle).
// GEMV fused: thread owns h = j+5*hp (<=7 rows), W2 from L1; parks in s_g2.
// Then h in 4 chunks of 8: a8/b8 from W1^T (uniform LDS broadcast), b8 ->
// s_b, barrier, accumulate w[5]/hp[5] with broadcast b128 reads.
// __launch_bounds__(256) single-arg: blocks<=256 threads, VGPR budget 256 --
// every spill this session came from a tighter (implicit or explicit) cap.
__global__ __launch_bounds__(BLOCK) void zhat_kernel(
    const float* __restrict__ obs, const float* __restrict__ ghat,
    const float* __restrict__ W1, const float* __restrict__ b1,
    const float* __restrict__ W2, const float* __restrict__ b2,
    float* __restrict__ zbuf, int zstride, int zoff, int B)
{
    __shared__ float s_W1t[HH * W1P];   // W1^T [h][d<24]
    __shared__ float s_b1[HH];
    __shared__ float s_w2s[HH];         // rowsum(W2)
    __shared__ float s_sb2;             // sum(b2)
    __shared__ float s_g2[SPB * G2S];   // W2@ghat per scene
    __shared__ float s_b[SPB * SBS];    // b rows: [scene][j][32] @ stride SBJ

    const int tid = threadIdx.x;

    // ---- stage W1^T (coalesced read), b1, w2s, sb2 ----
    for (int idx = tid; idx < 2 * DD * HH; idx += BLOCK) {
        const int h = idx & (HH - 1);   // idx = d*32 + h
        const int d = idx >> 5;
        s_W1t[h * W1P + d] = W1[idx];
    }
    if (tid < HH) {
        s_b1[tid] = b1[tid];
        float s = 0.f;
        const float4* p = reinterpret_cast<const float4*>(W2 + tid * EE);
        #pragma unroll
        for (int qq = 0; qq < EE / 4; ++qq) { float4 v = p[qq]; s += (v.x + v.y) + (v.z + v.w); }
        s_w2s[tid] = s;
    } else if (tid == HH) {
        float s = 0.f;
        #pragma unroll
        for (int e = 0; e < EE; ++e) s += b2[e];
        s_sb2 = s;
    }

    const int lane = tid & 63;
    const int wv   = tid >> 6;
    const int grp  = lane / 5;                 // 12 => idle lane
    const int j    = lane - grp * 5;
    const bool on  = (grp < 12);
    const int sBlk = wv * 12 + (on ? grp : 0); // LDS scene slot (clamped)
    const int i    = blockIdx.x * SPB + wv * 12 + grp;
    const bool act = on && (i < B);
    const int ic   = act ? i : (B - 1);        // clamp loads; stores guarded

    // ---- my obs row (12 floats; 5-lane group covers 60 contiguous) ----
    float o[DD];
    {
        const float4* p = reinterpret_cast<const float4*>(obs + (size_t)ic * (NB * DD) + j * DD);
        #pragma unroll
        for (int qq = 0; qq < 3; ++qq) {
            float4 v = p[qq];
            o[4*qq+0] = v.x; o[4*qq+1] = v.y; o[4*qq+2] = v.z; o[4*qq+3] = v.w;
        }
    }

    // ---- fused GEMV: g2[h] = W2[h,:].ghat_i for owned h = j+5*hp ----
    {
        float g2own[7];
        #pragma unroll
        for (int hp = 0; hp < 7; ++hp) g2own[hp] = 0.f;
        const float* grow = ghat + (size_t)ic * EE;
        #pragma unroll 1
        for (int ec = 0; ec < 4; ++ec) {          // 16 e per chunk
            float gc[16];
            const float4* gp = reinterpret_cast<const float4*>(grow + ec * 16);
            #pragma unroll
            for (int qq = 0; qq < 4; ++qq) {
                float4 v = gp[qq];
                gc[4*qq+0] = v.x; gc[4*qq+1] = v.y; gc[4*qq+2] = v.z; gc[4*qq+3] = v.w;
            }
            #pragma unroll
            for (int hp = 0; hp < 7; ++hp) {
                const int h = j + 5 * hp;
                if (h < HH) {                      // exec-masked tail
                    const float4* wp = reinterpret_cast<const float4*>(W2 + h * EE + ec * 16);
                    #pragma unroll
                    for (int qv = 0; qv < 4; ++qv) {
                        const float4 wvv = wp[qv];         // L1-hot (8 KB)
                        g2own[hp] += (gc[4*qv+0] * wvv.x + gc[4*qv+1] * wvv.y)
                                   + (gc[4*qv+2] * wvv.z + gc[4*qv+3] * wvv.w);
                    }
                }
            }
        }
        if (on) {
            #pragma unroll
            for (int hp = 0; hp < 7; ++hp) {
                const int h = j + 5 * hp;
                if (h < HH) s_g2[sBlk * G2S + h] = g2own[hp];
            }
        }
    }
    __syncthreads();   // weights + s_g2 ready

    float w[NB], hp5[NB];
    #pragma unroll
    for (int k = 0; k < NB; ++k) { w[k] = 0.f; hp5[k] = 0.f; }

    #pragma unroll 1
    for (int c = 0; c < 4; ++c) {
        // ---- a8/b8 for h = c*8..c*8+7 (uniform h -> broadcast LDS reads) ----
        float a8[8], b8[8];
        #pragma unroll
        for (int hq = 0; hq < 8; ++hq) {
            const int h = c * 8 + hq;
            const float* w1r = &s_W1t[h * W1P];
            const float4 t0 = *reinterpret_cast<const float4*>(w1r + 0);
            const float4 t1 = *reinterpret_cast<const float4*>(w1r + 4);
            const float4 t2 = *reinterpret_cast<const float4*>(w1r + 8);
            a8[hq] = s_b1[h]
                 + ((o[0]*t0.x + o[1]*t0.y) + (o[2]*t0.z + o[3]*t0.w))
                 + ((o[4]*t1.x + o[5]*t1.y) + (o[6]*t1.z + o[7]*t1.w))
                 + ((o[8]*t2.x + o[9]*t2.y) + (o[10]*t2.z + o[11]*t2.w));
            const float4 u0 = *reinterpret_cast<const float4*>(w1r + 12);
            const float4 u1 = *reinterpret_cast<const float4*>(w1r + 16);
            const float4 u2 = *reinterpret_cast<const float4*>(w1r + 20);
            b8[hq] = ((o[0]*u0.x + o[1]*u0.y) + (o[2]*u0.z + o[3]*u0.w))
                 + ((o[4]*u1.x + o[5]*u1.y) + (o[6]*u1.z + o[7]*u1.w))
                 + ((o[8]*u2.x + o[9]*u2.y) + (o[10]*u2.z + o[11]*u2.w));
        }
        if (on) {
            float4* dst = reinterpret_cast<float4*>(&s_b[sBlk * SBS + j * SBJ + c * 8]);
            dst[0] = make_float4(b8[0], b8[1], b8[2], b8[3]);
            dst[1] = make_float4(b8[4], b8[5], b8[6], b8[7]);
        }
        __syncthreads();   // chunk's b rows visible (disjoint slices per chunk)

        // ---- pair accumulation for my row j against all k ----
        float g2c[8], w2c[8];
        {
            const float4* gv4 = reinterpret_cast<const float4*>(&s_g2[sBlk * G2S + c * 8]);
            const float4 v0 = gv4[0], v1 = gv4[1];   // 5-lane broadcast
            g2c[0]=v0.x; g2c[1]=v0.y; g2c[2]=v0.z; g2c[3]=v0.w;
            g2c[4]=v1.x; g2c[5]=v1.y; g2c[6]=v1.z; g2c[7]=v1.w;
            const float4* up = reinterpret_cast<const float4*>(&s_w2s[c * 8]);
            const float4 u0 = up[0], u1 = up[1];
            w2c[0]=u0.x; w2c[1]=u0.y; w2c[2]=u0.z; w2c[3]=u0.w;
            w2c[4]=u1.x; w2c[5]=u1.y; w2c[6]=u1.z; w2c[7]=u1.w;
        }
        #pragma unroll
        for (int k = 0; k < NB; ++k) {
            const float4* bp = reinterpret_cast<const float4*>(&s_b[sBlk * SBS + k * SBJ + c * 8]);
            const float4 b0 = bp[0], b1v = bp[1];   // 5-lane broadcast reads
            const float bl[8] = {b0.x, b0.y, b0.z, b0.w, b1v.x, b1v.y, b1v.z, b1v.w};
            #pragma unroll
            for (int e = 0; e < 8; ++e) {
                const float hv = fmaxf(a8[e] + bl[e], 0.f);
                w[k]   += hv * g2c[e];
                hp5[k] += hv * w2c[e];
            }
        }
    }

    // ---- softmax across 5-lane group; thread owns row j (proven R13/R15) ----
    const int base5 = (on ? grp : 0) * 5;
    float mm = w[0];
    #pragma unroll
    for (int k = 1; k < NB; ++k) mm = fmaxf(mm, w[k]);
    float m = mm;
    #pragma unroll
    for (int k = 0; k < NB; ++k) m = fmaxf(m, __shfl(mm, base5 + k));

    float r = 0.f, z = 0.f;
    #pragma unroll
    for (int k = 0; k < NB; ++k) {
        const float e = __expf(w[k] - m);
        r += e;
        z += e * hp5[k];
    }
    float l = 0.f;
    #pragma unroll
    for (int k = 0; k < NB; ++k) l += __shfl(r, base5 + k);

    if (act)
        zbuf[(size_t)i * zstride + zoff + j] = (z + s_sb2 * r) / l;
}

// ---------------- K3: assemble output (proven R3 path) ----------------
__global__ __launch_bounds__(BLOCK) void assemble_kernel(
    const float* __restrict__ obs, const float* __restrict__ ghat,
    const float* __restrict__ zbuf, int zstride, int zoff,
    float* __restrict__ out, int B)
{
    __shared__ float s_obs[TILE * NB * DD];
    __shared__ float s_gh[TILE * EE];
    __shared__ float s_zh[TILE * NB];

    const int tid = threadIdx.x;
    const int r0 = blockIdx.x * TILE;
    const int rows = (B - r0 < TILE) ? (B - r0) : TILE;

    for (int t = tid; t < rows * NB * DD; t += BLOCK)
        s_obs[t] = obs[(size_t)r0 * NB * DD + t];
    for (int t = tid; t < rows * EE; t += BLOCK)
        s_gh[t] = ghat[(size_t)r0 * EE + t];
    for (int t = tid; t < rows * NB; t += BLOCK) {
        const int row = t / NB, k = t - row * NB;
        s_zh[t] = zbuf[(size_t)(r0 + row) * zstride + zoff + k];
    }
    __syncthreads();

    const size_t base = (size_t)r0 * OUTW;
    for (int t = tid; t < rows * OUTW; t += BLOCK) {
        const int il = t / OUTW;
        const int r  = t - il * OUTW;
        const int j  = r / ROW;
        const int rr = r - j * ROW;
        float v;
        if (rr < DD)           v = s_obs[il * NB * DD + j * DD + rr];
        else if (rr < DD + EE) v = s_gh[il * EE + (rr - DD)];
        else                   v = s_zh[il * NB + (rr - (DD + EE))];
        out[base + t] = v;
    }
}

extern "C" void kernel_launch(void* const* d_in, const int* in_sizes, int n_in,
                              void* d_out, int out_size, void* d_ws, size_t ws_size,
                              hipStream_t stream) {
    const float* obs  = (const float*)d_in[0];
    const float* ghat = (const float*)d_in[1];
    const float* W1   = (const float*)d_in[2];
    const float* b1   = (const float*)d_in[3];
    const float* W2   = (const float*)d_in[4];
    const float* b2   = (const float*)d_in[5];
    float* out = (float*)d_out;

    const int B = in_sizes[0] / (NB * DD);

    // zhat scratch: d_ws (2.6 MB) else stash in out row tails.
    float* zbuf; int zstride, zoff;
    if (ws_size >= (size_t)B * NB * sizeof(float)) {
        zbuf = (float*)d_ws; zstride = NB;   zoff = 0;
    } else {
        zbuf = out;          zstride = OUTW; zoff = OUTW - NB;
    }

    const int grid2 = (B + SPB - 1) / SPB;
    hipLaunchKernelGGL(zhat_kernel, dim3(grid2), dim3(BLOCK), 0, stream,
                       obs, ghat, W1, b1, W2, b2, zbuf, zstride, zoff, B);

    const int grid3 = (B + TILE - 1) / TILE;
    hipLaunchKernelGGL(assemble_kernel, dim3(grid3), dim3(BLOCK), 0, stream,
                       obs, ghat, zbuf, zstride, zoff, out, B);
}